// Round 13
// baseline (205.747 us; speedup 1.0000x reference)
//
#include <hip/hip_runtime.h>
#include <hip/hip_bf16.h>
#include <math.h>

#define NTOK 8192
#define DIM 256
#define KCB 4096
#define NCB (KCB / 128)    // 32 col-blocks in score GEMM
#define NKEY 4             // top-4 kept per (row, col-block)
#define NKROW (NCB * NKEY) // 128 u32 keys per row
#define DELTA 0.08f        // candidate window, raw-dot units (~20 sigma of bf16 noise + quant)
#define GTIE 2e-6          // fp64 cosine gap below which we run the bit-exact np chain
#define MAXC 16
#define NSCOB ((NTOK / 256) * NCB)    // 1024 score blocks (256-row x 128-col tiles)
#define NPAIRB 272                    // pairwise blocks: rb in [0,16), cb in [2rb,32)

typedef unsigned long long ull;
typedef unsigned short ushort;
typedef __attribute__((ext_vector_type(8))) short shortx8;   // 8 bf16 (4 VGPRs)
typedef __attribute__((ext_vector_type(4))) float floatx4;
typedef const __attribute__((address_space(1))) void* gas_cp;
typedef __attribute__((address_space(3))) void* las_p;

// ---- float <-> order-preserving u32 ----
__device__ __forceinline__ unsigned f2ord(float f) {
    unsigned u = __float_as_uint(f);
    return (u & 0x80000000u) ? ~u : (u | 0x80000000u);
}
__device__ __forceinline__ float ord2f(unsigned u) {
    unsigned b = (u & 0x80000000u) ? (u & 0x7FFFFFFFu) : ~u;
    return __uint_as_float(b);
}
__device__ __forceinline__ ushort f2bf(float f) {   // RNE fp32->bf16
    unsigned u = __float_as_uint(f);
    unsigned r = u + 0x7FFFu + ((u >> 16) & 1u);
    return (ushort)(r >> 16);
}

// ---- shared memory: A(256x64) + B(128x64) tiles alias epilogue storage ----
union TileSmem {
    struct { ushort a[256][64]; ushort b[128][64]; } t;   // 48 KB
    unsigned keys[256][33];                               // 33.8 KB (scores epi)
    struct { float rs[256]; float rm[256]; } red;         // 2 KB (pairwise epi)
};

// ---- async stage: 64 rows per wave (8 insts), XOR-swizzled chunks ----
__device__ __forceinline__ void stage_rows64(const ushort* __restrict__ gbase,
                                             ushort (*lds)[64], int wave, int lane,
                                             int kk) {
    int p = lane & 7;
    int rsub = lane >> 3;
    int kc = p ^ (rsub & 7);
    const ushort* src0 = gbase + (size_t)(wave * 64 + rsub) * DIM + kk + kc * 8;
#pragma unroll
    for (int c = 0; c < 8; ++c) {
        const ushort* src = src0 + (size_t)(c * 8) * DIM;
        __builtin_amdgcn_global_load_lds((gas_cp)src, (las_p)&lds[wave * 64 + c * 8][0],
                                         16, 0, 0);
    }
}
// ---- async stage: 32 rows per wave (4 insts) — B tile across 4 waves ----
__device__ __forceinline__ void stage_rows32(const ushort* __restrict__ gbase,
                                             ushort (*lds)[64], int wave, int lane,
                                             int kk) {
    int p = lane & 7;
    int rsub = lane >> 3;
    int kc = p ^ (rsub & 7);
    const ushort* src0 = gbase + (size_t)(wave * 32 + rsub) * DIM + kk + kc * 8;
#pragma unroll
    for (int c = 0; c < 4; ++c) {
        const ushort* src = src0 + (size_t)(c * 8) * DIM;
        __builtin_amdgcn_global_load_lds((gas_cp)src, (las_p)&lds[wave * 32 + c * 8][0],
                                         16, 0, 0);
    }
}
__device__ __forceinline__ shortx8 frag_read(const ushort (*lds)[64], int row,
                                             int lc) {
    return *(const shortx8*)&lds[row][(lc ^ (row & 7)) * 8];
}

// ---- numpy fp32 pairwise-norm helper: combine 16 accumulators exactly ----
__device__ __forceinline__ float np_combine(const float* racc) {
    float h0 = __fadd_rn(__fadd_rn(__fadd_rn(racc[0], racc[1]), __fadd_rn(racc[2], racc[3])),
                         __fadd_rn(__fadd_rn(racc[4], racc[5]), __fadd_rn(racc[6], racc[7])));
    float h1 = __fadd_rn(__fadd_rn(__fadd_rn(racc[8], racc[9]), __fadd_rn(racc[10], racc[11])),
                         __fadd_rn(__fadd_rn(racc[12], racc[13]), __fadd_rn(racc[14], racc[15])));
    float s = __fadd_rn(h0, h1);
    return fmaxf(sqrtf(s), 1e-12f);
}

// ---- fused prep: blocks [0,NTOK) = latent rows, [NTOK, NTOK+KCB) = codebook ----
__global__ __launch_bounds__(256) void prep(const float* __restrict__ lat,
                                            const float* __restrict__ cb,
                                            float* __restrict__ nrml,
                                            float* __restrict__ nrmc,
                                            ushort* __restrict__ latbf,
                                            ushort* __restrict__ cnbf,
                                            ushort* __restrict__ cbbf,
                                            float* __restrict__ sq,
                                            unsigned* __restrict__ counts) {
    int bid = blockIdx.x, t = threadIdx.x;
    if (bid < NTOK) {
        int n = bid;
        if (n < KCB / 256) counts[n * 256 + t] = 0u;
        const float* row = lat + (size_t)n * DIM;
        latbf[(size_t)n * DIM + t] = f2bf(row[t]);
        __shared__ float racc[16];
        if (t < 16) {
            int h = t >> 3, j = t & 7;
            const float* p = row + h * 128;
            float r = __fmul_rn(p[j], p[j]);
#pragma unroll 1
            for (int i = 8; i < 128; i += 8)
                r = __fadd_rn(r, __fmul_rn(p[i + j], p[i + j]));
            racc[t] = r;
        }
        __syncthreads();
        if (t == 0) nrml[n] = np_combine(racc);
    } else {
        int n = bid - NTOK;
        __shared__ float racc2[16];
        __shared__ double dacc[16];
        __shared__ float snrm;
        const float* row = cb + (size_t)n * DIM;
        if (t < 16) {
            int h = t >> 3, j = t & 7;
            const float* p = row + h * 128;
            float r = __fmul_rn(p[j], p[j]);
            double ds = 0.0;
#pragma unroll 1
            for (int i = 8; i < 128; i += 8)
                r = __fadd_rn(r, __fmul_rn(p[i + j], p[i + j]));
#pragma unroll 1
            for (int i = 0; i < 128; i += 8) { double v = (double)p[i + j]; ds += v * v; }
            racc2[t] = r; dacc[t] = ds;
        }
        __syncthreads();
        if (t == 0) {
            float nr = np_combine(racc2);
            snrm = nr; nrmc[n] = nr;
            double ds = 0.0;
            for (int i = 0; i < 16; ++i) ds += dacc[i];
            sq[n] = (float)ds;
        }
        __syncthreads();
        float c = row[t];
        cnbf[(size_t)n * DIM + t] = f2bf(c / snrm);
        cbbf[(size_t)n * DIM + t] = f2bf(c);
    }
}

// ---- merged GEMM kernel: 256 threads, 4 waves x (64 rows x 128 cols) ----
// 256x128 tile; A (256 rows) + B (128 rows) both staged via global_load_lds.
// blocks [0, NSCOB): score tiles -> top-4 keys per (row, col-block)
// blocks [NSCOB, +NPAIRB): codebook pairwise triangle tiles -> sum/min
__global__ __launch_bounds__(256) void gemms(const ushort* __restrict__ latbf,
                                             const ushort* __restrict__ cnbf,
                                             const ushort* __restrict__ cbbf,
                                             const float* __restrict__ sq,
                                             unsigned* __restrict__ keysw,
                                             float* __restrict__ psumw,
                                             unsigned* __restrict__ pminw) {
    __shared__ TileSmem sm;
    int tid = threadIdx.x;
    int wave = tid >> 6, lane = tid & 63;
    int quad = lane >> 4, l15 = lane & 15;
    int wrow = wave * 64;
    bool isScore = blockIdx.x < NSCOB;
    int rowBase, colBase, tri = 0;
    const ushort *gA, *gB;
    if (isScore) {
        int cbk = blockIdx.x & (NCB - 1);
        int rbk = blockIdx.x >> 5;
        rowBase = rbk * 256; colBase = cbk * 128;
        gA = latbf + (size_t)rowBase * DIM;
        gB = cnbf + (size_t)colBase * DIM;
    } else {
        tri = blockIdx.x - NSCOB;
        int rb = 0;
        while ((rb + 1) * (33 - (rb + 1)) <= tri) ++rb;   // offset(rb) = rb*(33-rb)
        int cbk = tri - rb * (33 - rb) + 2 * rb;
        rowBase = rb * 256; colBase = cbk * 128;
        gA = cbbf + (size_t)rowBase * DIM;
        gB = cbbf + (size_t)colBase * DIM;
    }
    floatx4 acc[4][8];
#pragma unroll
    for (int m = 0; m < 4; ++m)
#pragma unroll
        for (int n = 0; n < 8; ++n) acc[m][n] = (floatx4){0.f, 0.f, 0.f, 0.f};
#pragma unroll 1
    for (int kk = 0; kk < DIM; kk += 64) {
        __syncthreads();
        stage_rows64(gA, sm.t.a, wave, lane, kk);   // A: 4 waves x 64 rows
        stage_rows32(gB, sm.t.b, wave, lane, kk);   // B: 4 waves x 32 rows
        __syncthreads();
#pragma unroll
        for (int s = 0; s < 2; ++s) {
            shortx8 af[4];
#pragma unroll
            for (int mt = 0; mt < 4; ++mt)
                af[mt] = frag_read(sm.t.a, wrow + mt * 16 + l15, s * 4 + quad);
#pragma unroll
            for (int nt = 0; nt < 8; ++nt) {
                shortx8 bfr = frag_read(sm.t.b, nt * 16 + l15, s * 4 + quad);
#pragma unroll
                for (int mt = 0; mt < 4; ++mt)
                    acc[mt][nt] = __builtin_amdgcn_mfma_f32_16x16x32_bf16(
                        af[mt], bfr, acc[mt][nt], 0, 0, 0);
            }
        }
    }
    __syncthreads();   // tiles dead; reuse LDS for epilogue
    if (isScore) {
        unsigned colp[8];
#pragma unroll
        for (int nt = 0; nt < 8; ++nt)
            colp[nt] = 4095u - (unsigned)(colBase + nt * 16 + l15);
#pragma unroll
        for (int mt = 0; mt < 4; ++mt)
#pragma unroll
            for (int reg = 0; reg < 4; ++reg) {
                unsigned b1 = 0u, b2 = 0u;
#pragma unroll
                for (int nt = 0; nt < 8; ++nt) {
                    unsigned key = (f2ord(acc[mt][nt][reg]) & 0xFFFFF000u) | colp[nt];
                    unsigned lo = min(key, b1);
                    b1 = max(key, b1);
                    b2 = max(lo, b2);
                }
                int row = wrow + mt * 16 + quad * 4 + reg;
                uint2 kv; kv.x = b1; kv.y = b2;
                *(uint2*)&sm.keys[row][l15 * 2] = kv;
            }
        __syncthreads();
        {
            unsigned a0 = 0, a1 = 0, a2 = 0, a3 = 0;
#pragma unroll
            for (int j = 0; j < 8; ++j) {
                uint4 v4 = *(const uint4*)&sm.keys[tid][j * 4];
                unsigned vs[4] = {v4.x, v4.y, v4.z, v4.w};
#pragma unroll
                for (int q = 0; q < 4; ++q) {
                    unsigned v = vs[q];
                    unsigned n0 = min(v, a0); a0 = max(v, a0);
                    unsigned n1 = min(n0, a1); a1 = max(n0, a1);
                    unsigned n2 = min(n1, a2); a2 = max(n1, a2);
                    a3 = max(n2, a3);
                }
            }
            size_t base = (size_t)(rowBase + tid) * NKROW + (blockIdx.x & (NCB - 1)) * NKEY;
            uint4 o; o.x = a0; o.y = a1; o.z = a2; o.w = a3;
            *(uint4*)&keysw[base] = o;
        }
    } else {
        float lsum = 0.f, lmin = INFINITY;
#pragma unroll
        for (int mt = 0; mt < 4; ++mt)
#pragma unroll
            for (int reg = 0; reg < 4; ++reg) {
                int i = rowBase + wrow + mt * 16 + quad * 4 + reg;
                float sqi = sq[i];
#pragma unroll
                for (int nt = 0; nt < 8; ++nt) {
                    int j = colBase + nt * 16 + l15;
                    float d2 = sqi + sq[j] - 2.0f * acc[mt][nt][reg];
                    float d = sqrtf(fmaxf(d2, 0.0f));
                    bool use = i < j;
                    lsum += use ? d : 0.f;
                    lmin = fminf(lmin, use ? d : INFINITY);
                }
            }
        sm.red.rs[tid] = lsum; sm.red.rm[tid] = lmin; __syncthreads();
        for (int s = 128; s > 0; s >>= 1) {
            if (tid < s) {
                sm.red.rs[tid] += sm.red.rs[tid + s];
                sm.red.rm[tid] = fminf(sm.red.rm[tid], sm.red.rm[tid + s]);
            }
            __syncthreads();
        }
        if (tid == 0) { psumw[tri] = sm.red.rs[0]; pminw[tri] = f2ord(sm.red.rm[0]); }
    }
}

// ---- wave-per-row argmax resolve + fused quantized gather/mse ----
__global__ __launch_bounds__(256) void argmax_resolve(const float* __restrict__ lat,
                                                      const float* __restrict__ cb,
                                                      const float* __restrict__ nrml,
                                                      const float* __restrict__ nrmc,
                                                      const unsigned* __restrict__ keysw,
                                                      float* __restrict__ outidx,
                                                      float* __restrict__ outq,
                                                      unsigned* __restrict__ counts,
                                                      float* __restrict__ selw,
                                                      float* __restrict__ msew) {
    __shared__ int scand[4][MAXC];
    __shared__ double sc64[4][MAXC];
    int wid = threadIdx.x >> 6, lane = threadIdx.x & 63;
    int n = blockIdx.x * 4 + wid;
    const unsigned* kr = keysw + (size_t)n * NKROW;
    uint2 kv = *(const uint2*)(kr + lane * 2);
    unsigned m = max(kv.x, kv.y);
#pragma unroll
    for (int off = 1; off < 64; off <<= 1) {
        unsigned o = __shfl_xor(m, off, 64);
        m = max(m, o);
    }
    float v1 = ord2f(m & 0xFFFFF000u);
    float thresh = v1 - DELTA;
    bool p0 = ord2f(kv.x & 0xFFFFF000u) >= thresh;
    bool p1 = ord2f(kv.y & 0xFFFFF000u) >= thresh;
    ull b0 = __ballot(p0), b1 = __ballot(p1);
    int below0 = __builtin_amdgcn_mbcnt_hi((unsigned)(b0 >> 32),
                 __builtin_amdgcn_mbcnt_lo((unsigned)b0, 0));
    int below1 = __builtin_amdgcn_mbcnt_hi((unsigned)(b1 >> 32),
                 __builtin_amdgcn_mbcnt_lo((unsigned)b1, 0));
    int base1 = __popcll(b0);
    int nc = base1 + __popcll(b1);
    if (p0 && below0 < MAXC)
        scand[wid][below0] = 4095 - (int)(kv.x & 0xFFFu);
    if (p1 && base1 + below1 < MAXC)
        scand[wid][base1 + below1] = 4095 - (int)(kv.y & 0xFFFu);
    nc = nc < MAXC ? nc : MAXC;
    __threadfence_block();
    float nx = nrml[n];
    int d0 = lane * 4;
    float4 xv = *(const float4*)(lat + (size_t)n * DIM + d0);
    int idx; float selcos;
    if (nc <= 1) {
        idx = 4095 - (int)(m & 0xFFFu);
        selcos = v1 / nx;
    } else {
        float la0 = xv.x / nx, la1 = xv.y / nx, la2 = xv.z / nx, la3 = xv.w / nx;
        for (int c = 0; c < nc; ++c) {
            int k = scand[wid][c];
            float nk = nrmc[k];
            float4 cv = *(const float4*)(cb + (size_t)k * DIM + d0);
            double part = (double)(cv.x / nk) * la0 + (double)(cv.y / nk) * la1 +
                          (double)(cv.z / nk) * la2 + (double)(cv.w / nk) * la3;
#pragma unroll
            for (int off = 1; off < 64; off <<= 1) part += __shfl_xor(part, off, 64);
            if (lane == 0) sc64[wid][c] = part;
        }
        __threadfence_block();
        double best64 = -1e300;
        for (int c = 0; c < nc; ++c) best64 = fmax(best64, sc64[wid][c]);
        int nrisk = 0;
        for (int c = 0; c < nc; ++c) if (sc64[wid][c] >= best64 - GTIE) ++nrisk;
        if (nrisk == 1) {
            idx = 0x7FFFFFFF; selcos = 0.f;
            for (int c = 0; c < nc; ++c)
                if (sc64[wid][c] >= best64 - GTIE) { idx = scand[wid][c]; selcos = (float)sc64[wid][c]; }
        } else {
            // rare: bit-exact np fp32 chains, one candidate per lane (R4 semantics)
            ull keyf = 0ull, keym = 0ull;
            if (lane < nc && sc64[wid][lane] >= best64 - GTIE) {
                int k = scand[wid][lane];
                const float* cr = cb + (size_t)k * DIM;
                const float* x = lat + (size_t)n * DIM;
                float nk = nrmc[k];
                float af = 0.f, am = 0.f;
                for (int d = 0; d < DIM; ++d) {
                    float la = x[d] / nx;
                    float cv = cr[d] / nk;
                    af = fmaf(la, cv, af);
                    am = __fadd_rn(am, __fmul_rn(la, cv));
                }
                float df = __fsub_rn(2.0f, __fmul_rn(2.0f, af));
                float dm = __fsub_rn(2.0f, __fmul_rn(2.0f, am));
                keyf = ((ull)(0xFFFFFFFFu - f2ord(df)) << 32) | (ull)(0xFFFFFFFFu - (unsigned)k);
                keym = ((ull)(0xFFFFFFFFu - f2ord(dm)) << 32) | (ull)(0xFFFFFFFFu - (unsigned)k);
            }
#pragma unroll
            for (int off = 1; off < 64; off <<= 1) {
                ull of = __shfl_xor(keyf, off, 64);
                ull om = __shfl_xor(keym, off, 64);
                keyf = of > keyf ? of : keyf;
                keym = om > keym ? om : keym;
            }
            int colf = (int)(0xFFFFFFFFu - (unsigned)(keyf & 0xFFFFFFFFull));
            int colm = (int)(0xFFFFFFFFu - (unsigned)(keym & 0xFFFFFFFFull));
            idx = colf < colm ? colf : colm;
            selcos = 0.f;
            for (int c = 0; c < nc; ++c)
                if (scand[wid][c] == idx) selcos = (float)sc64[wid][c];
        }
    }
    // fused gather: idx is wave-uniform on every path
    float4 qv = *(const float4*)(cb + (size_t)idx * DIM + d0);
    *(float4*)(outq + (size_t)n * DIM + d0) = qv;
    float dx = xv.x - qv.x, dy = xv.y - qv.y, dz = xv.z - qv.z, dw = xv.w - qv.w;
    float msep = fmaf(dx, dx, fmaf(dy, dy, fmaf(dz, dz, dw * dw)));
#pragma unroll
    for (int off = 1; off < 64; off <<= 1) msep += __shfl_xor(msep, off, 64);
    if (lane == 0) {
        outidx[n] = (float)idx;
        atomicAdd(&counts[idx], 1u);
        selw[n] = selcos;
        msew[n] = msep;
    }
}

// ---- scalars: reduce all partial arrays ----
__global__ void finalize(const unsigned* __restrict__ counts,
                         const float* __restrict__ selw,
                         const float* __restrict__ msew,
                         const float* __restrict__ psumw,
                         const unsigned* __restrict__ pminw,
                         float* __restrict__ outs) {
    int t = threadIdx.x;
    __shared__ float red[256];
    float h = 0.f;
    for (int k = t; k < KCB; k += 256) {
        float p = (float)counts[k] * (1.0f / (float)NTOK);
        h += p * logf(p + 1e-10f);
    }
    red[t] = h; __syncthreads();
    for (int s = 128; s > 0; s >>= 1) { if (t < s) red[t] += red[t + s]; __syncthreads(); }
    float entNeg = red[0];
    __syncthreads();
    float ssel = 0.f;
    for (int k = t; k < NTOK; k += 256) ssel += selw[k];
    red[t] = ssel; __syncthreads();
    for (int s = 128; s > 0; s >>= 1) { if (t < s) red[t] += red[t + s]; __syncthreads(); }
    float selSum = red[0];
    __syncthreads();
    float sm = 0.f;
    for (int k = t; k < NTOK; k += 256) sm += msew[k];
    red[t] = sm; __syncthreads();
    for (int s = 128; s > 0; s >>= 1) { if (t < s) red[t] += red[t + s]; __syncthreads(); }
    float mseSum = red[0];
    __syncthreads();
    float ps = 0.f;
    for (int k = t; k < NPAIRB; k += 256) ps += psumw[k];
    red[t] = ps; __syncthreads();
    for (int s = 128; s > 0; s >>= 1) { if (t < s) red[t] += red[t + s]; __syncthreads(); }
    float pairSum = red[0];
    __syncthreads();
    unsigned pm = 0xFFFFFFFFu;
    for (int k = t; k < NPAIRB; k += 256) pm = min(pm, pminw[k]);
    ((unsigned*)red)[t] = pm; __syncthreads();
    for (int s = 128; s > 0; s >>= 1) {
        if (t < s) ((unsigned*)red)[t] = min(((unsigned*)red)[t], ((unsigned*)red)[t + s]);
        __syncthreads();
    }
    unsigned pairMin = ((unsigned*)red)[0];
    if (t == 0) {
        float mse = mseSum / (float)(NTOK * DIM);
        outs[0] = 0.25f * mse;
        outs[1] = mse;
        outs[2] = expf(-entNeg);
        outs[3] = selSum / (float)NTOK;
        outs[4] = pairSum * 2.0f / ((float)KCB * (float)(KCB - 1));
        outs[5] = ord2f(pairMin);
    }
}

extern "C" void kernel_launch(void* const* d_in, const int* in_sizes, int n_in,
                              void* d_out, int out_size, void* d_ws, size_t ws_size,
                              hipStream_t stream) {
    const float* latent = (const float*)d_in[0];    // [8192,256]
    const float* codebook = (const float*)d_in[1];  // [4096,256]
    float* out = (float*)d_out;
    float* outq = out;
    float* outidx = out + (size_t)NTOK * DIM;
    float* outs = outidx + NTOK;

    unsigned* keysw = (unsigned*)d_ws;                        // 128*8192 u32 = 4 MB
    ushort* latbf = (ushort*)(keysw + (size_t)NKROW * NTOK);  // 4 MB
    ushort* cnbf = latbf + (size_t)NTOK * DIM;                // 2 MB
    ushort* cbbf = cnbf + (size_t)KCB * DIM;                  // 2 MB
    float* nrml = (float*)(cbbf + (size_t)KCB * DIM);         // 8192
    float* nrmc = nrml + NTOK;                                // 4096
    float* sq = nrmc + KCB;                                   // 4096
    unsigned* counts = (unsigned*)(sq + KCB);                 // 4096
    float* selw = (float*)(counts + KCB);                     // 8192
    float* msew = selw + NTOK;                                // 8192
    float* psumw = msew + NTOK;                               // 272
    unsigned* pminw = (unsigned*)(psumw + NPAIRB);            // 272

    hipLaunchKernelGGL(prep, dim3(NTOK + KCB), dim3(256), 0, stream,
                       latent, codebook, nrml, nrmc, latbf, cnbf, cbbf, sq, counts);
    hipLaunchKernelGGL(gemms, dim3(NSCOB + NPAIRB), dim3(256), 0, stream,
                       latbf, cnbf, cbbf, sq, keysw, psumw, pminw);
    hipLaunchKernelGGL(argmax_resolve, dim3(NTOK / 4), dim3(256), 0, stream,
                       latent, codebook, nrml, nrmc, keysw, outidx, outq, counts, selw, msew);
    hipLaunchKernelGGL(finalize, dim3(1), dim3(256), 0, stream, counts, selw, msew, psumw, pminw, outs);
}

// Round 14
// 175.161 us; speedup vs baseline: 1.1746x; 1.1746x over previous
//
#include <hip/hip_runtime.h>
#include <hip/hip_bf16.h>
#include <math.h>

#define NTOK 8192
#define DIM 256
#define KCB 4096
#define NCB (KCB / 128)    // 32 col-blocks in score GEMM
#define NKEY 4             // top-4 kept per (row, col-block)
#define NKROW (NCB * NKEY) // 128 u32 keys per row
#define DELTA 0.08f        // candidate window, raw-dot units (~20 sigma of bf16 noise + quant)
#define GTIE 2e-6          // fp64 cosine gap below which we run the bit-exact np chain
#define MAXC 16
#define NPAIRB (NCB * (NCB + 1) / 2)  // 528 upper-triangle pairwise blocks
#define NSCOB (NCB * (NTOK / 128))    // 2048 score blocks

typedef unsigned long long ull;
typedef unsigned short ushort;
typedef __attribute__((ext_vector_type(8))) short shortx8;   // 8 bf16 (4 VGPRs)
typedef __attribute__((ext_vector_type(4))) float floatx4;
typedef const __attribute__((address_space(1))) void* gas_cp;
typedef __attribute__((address_space(3))) void* las_p;

// ---- float <-> order-preserving u32 ----
__device__ __forceinline__ unsigned f2ord(float f) {
    unsigned u = __float_as_uint(f);
    return (u & 0x80000000u) ? ~u : (u | 0x80000000u);
}
__device__ __forceinline__ float ord2f(unsigned u) {
    unsigned b = (u & 0x80000000u) ? (u & 0x7FFFFFFFu) : ~u;
    return __uint_as_float(b);
}
__device__ __forceinline__ ushort f2bf(float f) {   // RNE fp32->bf16
    unsigned u = __float_as_uint(f);
    unsigned r = u + 0x7FFFu + ((u >> 16) & 1u);
    return (ushort)(r >> 16);
}

// ---- shared memory: GEMM tiles alias epilogue storage ----
union TileSmem {
    struct { ushort a[128][64]; ushort b[128][64]; } t;   // 32 KB
    unsigned keys[128][33];                               // 16.9 KB (scores epi)
    struct { float rs[128]; float rm[128]; } red;         // 1 KB (pairwise epi)
};

// ---- async stage: 128 rows x 64 ushorts, XOR-swizzled chunks, 2-wave block ----
__device__ __forceinline__ void stage_tile(const ushort* __restrict__ gbase,
                                           ushort (*lds)[64], int wave, int lane,
                                           int kk) {
    int p = lane & 7;
    int rsub = lane >> 3;
    int kc = p ^ (rsub & 7);
    const ushort* src0 = gbase + (size_t)(wave * 64 + rsub) * DIM + kk + kc * 8;
#pragma unroll
    for (int c = 0; c < 8; ++c) {
        const ushort* src = src0 + (size_t)(c * 8) * DIM;
        __builtin_amdgcn_global_load_lds((gas_cp)src, (las_p)&lds[wave * 64 + c * 8][0],
                                         16, 0, 0);
    }
}
__device__ __forceinline__ shortx8 frag_read(const ushort (*lds)[64], int row,
                                             int lc) {
    return *(const shortx8*)&lds[row][(lc ^ (row & 7)) * 8];
}

// ---- numpy fp32 pairwise-norm helper: combine 16 accumulators exactly ----
__device__ __forceinline__ float np_combine(const float* racc) {
    float h0 = __fadd_rn(__fadd_rn(__fadd_rn(racc[0], racc[1]), __fadd_rn(racc[2], racc[3])),
                         __fadd_rn(__fadd_rn(racc[4], racc[5]), __fadd_rn(racc[6], racc[7])));
    float h1 = __fadd_rn(__fadd_rn(__fadd_rn(racc[8], racc[9]), __fadd_rn(racc[10], racc[11])),
                         __fadd_rn(__fadd_rn(racc[12], racc[13]), __fadd_rn(racc[14], racc[15])));
    float s = __fadd_rn(h0, h1);
    return fmaxf(sqrtf(s), 1e-12f);
}

// ---- fused prep: blocks [0,NTOK) = latent rows, [NTOK, NTOK+KCB) = codebook ----
__global__ __launch_bounds__(256) void prep(const float* __restrict__ lat,
                                            const float* __restrict__ cb,
                                            float* __restrict__ nrml,
                                            float* __restrict__ nrmc,
                                            ushort* __restrict__ latbf,
                                            ushort* __restrict__ cnbf,
                                            ushort* __restrict__ cbbf,
                                            float* __restrict__ sq,
                                            unsigned* __restrict__ counts) {
    int bid = blockIdx.x, t = threadIdx.x;
    if (bid < NTOK) {
        int n = bid;
        if (n < KCB / 256) counts[n * 256 + t] = 0u;
        const float* row = lat + (size_t)n * DIM;
        latbf[(size_t)n * DIM + t] = f2bf(row[t]);
        __shared__ float racc[16];
        if (t < 16) {
            int h = t >> 3, j = t & 7;
            const float* p = row + h * 128;
            float r = __fmul_rn(p[j], p[j]);
#pragma unroll 1
            for (int i = 8; i < 128; i += 8)
                r = __fadd_rn(r, __fmul_rn(p[i + j], p[i + j]));
            racc[t] = r;
        }
        __syncthreads();
        if (t == 0) nrml[n] = np_combine(racc);
    } else {
        int n = bid - NTOK;
        __shared__ float racc2[16];
        __shared__ double dacc[16];
        __shared__ float snrm;
        const float* row = cb + (size_t)n * DIM;
        if (t < 16) {
            int h = t >> 3, j = t & 7;
            const float* p = row + h * 128;
            float r = __fmul_rn(p[j], p[j]);
            double ds = 0.0;
#pragma unroll 1
            for (int i = 8; i < 128; i += 8)
                r = __fadd_rn(r, __fmul_rn(p[i + j], p[i + j]));
#pragma unroll 1
            for (int i = 0; i < 128; i += 8) { double v = (double)p[i + j]; ds += v * v; }
            racc2[t] = r; dacc[t] = ds;
        }
        __syncthreads();
        if (t == 0) {
            float nr = np_combine(racc2);
            snrm = nr; nrmc[n] = nr;
            double ds = 0.0;
            for (int i = 0; i < 16; ++i) ds += dacc[i];
            sq[n] = (float)ds;
        }
        __syncthreads();
        float c = row[t];
        cnbf[(size_t)n * DIM + t] = f2bf(c / snrm);
        cbbf[(size_t)n * DIM + t] = f2bf(c);
    }
}

// ---- merged GEMM kernel: 128 threads, 2 waves x (64 rows x 128 cols) ----
// blocks [0, NSCOB): score tiles (latbf x cnbf) -> top-4 keys per (row, colblk)
// blocks [NSCOB, +NPAIRB): codebook pairwise upper-triangle tiles -> sum/min
__global__ __launch_bounds__(128, 2) void gemms(const ushort* __restrict__ latbf,
                                                const ushort* __restrict__ cnbf,
                                                const ushort* __restrict__ cbbf,
                                                const float* __restrict__ sq,
                                                unsigned* __restrict__ keysw,
                                                float* __restrict__ psumw,
                                                unsigned* __restrict__ pminw) {
    __shared__ TileSmem sm;
    int tid = threadIdx.x;
    int wave = tid >> 6, lane = tid & 63;
    int quad = lane >> 4, l15 = lane & 15;
    int wrow = wave * 64;
    bool isScore = blockIdx.x < NSCOB;
    int rowBase, colBase, tri = 0;
    const ushort *gA, *gB;
    if (isScore) {
        int cbk = blockIdx.x & (NCB - 1);
        int rbk = blockIdx.x >> 5;
        rowBase = rbk * 128; colBase = cbk * 128;
        gA = latbf + (size_t)rowBase * DIM;
        gB = cnbf + (size_t)colBase * DIM;
    } else {
        tri = blockIdx.x - NSCOB;
        int a = (int)((sqrtf(8.f * tri + 1.f) - 1.f) * 0.5f);
        while ((a + 1) * (a + 2) / 2 <= tri) ++a;
        while (a * (a + 1) / 2 > tri) --a;
        int b = tri - a * (a + 1) / 2;   // a >= b
        rowBase = b * 128; colBase = a * 128;
        gA = cbbf + (size_t)rowBase * DIM;
        gB = cbbf + (size_t)colBase * DIM;
    }
    floatx4 acc[4][8];
#pragma unroll
    for (int m = 0; m < 4; ++m)
#pragma unroll
        for (int n = 0; n < 8; ++n) acc[m][n] = (floatx4){0.f, 0.f, 0.f, 0.f};
#pragma unroll 1
    for (int kk = 0; kk < DIM; kk += 64) {
        __syncthreads();
        stage_tile(gA, sm.t.a, wave, lane, kk);
        stage_tile(gB, sm.t.b, wave, lane, kk);
        __syncthreads();
#pragma unroll
        for (int s = 0; s < 2; ++s) {
            shortx8 af[4];
#pragma unroll
            for (int mt = 0; mt < 4; ++mt)
                af[mt] = frag_read(sm.t.a, wrow + mt * 16 + l15, s * 4 + quad);
#pragma unroll
            for (int nt = 0; nt < 8; ++nt) {
                shortx8 bfr = frag_read(sm.t.b, nt * 16 + l15, s * 4 + quad);
#pragma unroll
                for (int mt = 0; mt < 4; ++mt)
                    acc[mt][nt] = __builtin_amdgcn_mfma_f32_16x16x32_bf16(
                        af[mt], bfr, acc[mt][nt], 0, 0, 0);
            }
        }
    }
    __syncthreads();   // tiles dead; reuse LDS for epilogue
    if (isScore) {
        unsigned colp[8];
#pragma unroll
        for (int nt = 0; nt < 8; ++nt)
            colp[nt] = 4095u - (unsigned)(colBase + nt * 16 + l15);
#pragma unroll
        for (int mt = 0; mt < 4; ++mt)
#pragma unroll
            for (int reg = 0; reg < 4; ++reg) {
                unsigned b1 = 0u, b2 = 0u;
#pragma unroll
                for (int nt = 0; nt < 8; ++nt) {
                    unsigned key = (f2ord(acc[mt][nt][reg]) & 0xFFFFF000u) | colp[nt];
                    unsigned lo = min(key, b1);
                    b1 = max(key, b1);
                    b2 = max(lo, b2);
                }
                int row = wrow + mt * 16 + quad * 4 + reg;
                uint2 kv; kv.x = b1; kv.y = b2;
                *(uint2*)&sm.keys[row][l15 * 2] = kv;
            }
        __syncthreads();
        {
            unsigned a0 = 0, a1 = 0, a2 = 0, a3 = 0;
#pragma unroll
            for (int j = 0; j < 8; ++j) {
                uint4 v4 = *(const uint4*)&sm.keys[tid][j * 4];
                unsigned vs[4] = {v4.x, v4.y, v4.z, v4.w};
#pragma unroll
                for (int q = 0; q < 4; ++q) {
                    unsigned v = vs[q];
                    unsigned n0 = min(v, a0); a0 = max(v, a0);
                    unsigned n1 = min(n0, a1); a1 = max(n0, a1);
                    unsigned n2 = min(n1, a2); a2 = max(n1, a2);
                    a3 = max(n2, a3);
                }
            }
            size_t base = (size_t)(rowBase + tid) * NKROW + (blockIdx.x & (NCB - 1)) * NKEY;
            uint4 o; o.x = a0; o.y = a1; o.z = a2; o.w = a3;
            *(uint4*)&keysw[base] = o;
        }
    } else {
        float lsum = 0.f, lmin = INFINITY;
#pragma unroll
        for (int mt = 0; mt < 4; ++mt)
#pragma unroll
            for (int reg = 0; reg < 4; ++reg) {
                int i = rowBase + wrow + mt * 16 + quad * 4 + reg;
                float sqi = sq[i];
#pragma unroll
                for (int nt = 0; nt < 8; ++nt) {
                    int j = colBase + nt * 16 + l15;
                    float d2 = sqi + sq[j] - 2.0f * acc[mt][nt][reg];
                    float d = sqrtf(fmaxf(d2, 0.0f));
                    bool use = i < j;
                    lsum += use ? d : 0.f;
                    lmin = fminf(lmin, use ? d : INFINITY);
                }
            }
        sm.red.rs[tid] = lsum; sm.red.rm[tid] = lmin; __syncthreads();
        for (int s = 64; s > 0; s >>= 1) {
            if (tid < s) {
                sm.red.rs[tid] += sm.red.rs[tid + s];
                sm.red.rm[tid] = fminf(sm.red.rm[tid], sm.red.rm[tid + s]);
            }
            __syncthreads();
        }
        if (tid == 0) { psumw[tri] = sm.red.rs[0]; pminw[tri] = f2ord(sm.red.rm[0]); }
    }
}

// ---- wave-per-row argmax resolve + fused quantized gather/mse ----
__global__ __launch_bounds__(256) void argmax_resolve(const float* __restrict__ lat,
                                                      const float* __restrict__ cb,
                                                      const float* __restrict__ nrml,
                                                      const float* __restrict__ nrmc,
                                                      const unsigned* __restrict__ keysw,
                                                      float* __restrict__ outidx,
                                                      float* __restrict__ outq,
                                                      unsigned* __restrict__ counts,
                                                      float* __restrict__ selw,
                                                      float* __restrict__ msew) {
    __shared__ int scand[4][MAXC];
    __shared__ double sc64[4][MAXC];
    int wid = threadIdx.x >> 6, lane = threadIdx.x & 63;
    int n = blockIdx.x * 4 + wid;
    const unsigned* kr = keysw + (size_t)n * NKROW;
    uint2 kv = *(const uint2*)(kr + lane * 2);
    unsigned m = max(kv.x, kv.y);
#pragma unroll
    for (int off = 1; off < 64; off <<= 1) {
        unsigned o = __shfl_xor(m, off, 64);
        m = max(m, o);
    }
    float v1 = ord2f(m & 0xFFFFF000u);
    float thresh = v1 - DELTA;
    bool p0 = ord2f(kv.x & 0xFFFFF000u) >= thresh;
    bool p1 = ord2f(kv.y & 0xFFFFF000u) >= thresh;
    ull b0 = __ballot(p0), b1 = __ballot(p1);
    int below0 = __builtin_amdgcn_mbcnt_hi((unsigned)(b0 >> 32),
                 __builtin_amdgcn_mbcnt_lo((unsigned)b0, 0));
    int below1 = __builtin_amdgcn_mbcnt_hi((unsigned)(b1 >> 32),
                 __builtin_amdgcn_mbcnt_lo((unsigned)b1, 0));
    int base1 = __popcll(b0);
    int nc = base1 + __popcll(b1);
    if (p0 && below0 < MAXC)
        scand[wid][below0] = 4095 - (int)(kv.x & 0xFFFu);
    if (p1 && base1 + below1 < MAXC)
        scand[wid][base1 + below1] = 4095 - (int)(kv.y & 0xFFFu);
    nc = nc < MAXC ? nc : MAXC;
    __threadfence_block();
    float nx = nrml[n];
    int d0 = lane * 4;
    float4 xv = *(const float4*)(lat + (size_t)n * DIM + d0);
    int idx; float selcos;
    if (nc <= 1) {
        idx = 4095 - (int)(m & 0xFFFu);
        selcos = v1 / nx;
    } else {
        float la0 = xv.x / nx, la1 = xv.y / nx, la2 = xv.z / nx, la3 = xv.w / nx;
        for (int c = 0; c < nc; ++c) {
            int k = scand[wid][c];
            float nk = nrmc[k];
            float4 cv = *(const float4*)(cb + (size_t)k * DIM + d0);
            double part = (double)(cv.x / nk) * la0 + (double)(cv.y / nk) * la1 +
                          (double)(cv.z / nk) * la2 + (double)(cv.w / nk) * la3;
#pragma unroll
            for (int off = 1; off < 64; off <<= 1) part += __shfl_xor(part, off, 64);
            if (lane == 0) sc64[wid][c] = part;
        }
        __threadfence_block();
        double best64 = -1e300;
        for (int c = 0; c < nc; ++c) best64 = fmax(best64, sc64[wid][c]);
        int nrisk = 0;
        for (int c = 0; c < nc; ++c) if (sc64[wid][c] >= best64 - GTIE) ++nrisk;
        if (nrisk == 1) {
            idx = 0x7FFFFFFF; selcos = 0.f;
            for (int c = 0; c < nc; ++c)
                if (sc64[wid][c] >= best64 - GTIE) { idx = scand[wid][c]; selcos = (float)sc64[wid][c]; }
        } else {
            // rare: bit-exact np fp32 chains, one candidate per lane (R4 semantics)
            ull keyf = 0ull, keym = 0ull;
            if (lane < nc && sc64[wid][lane] >= best64 - GTIE) {
                int k = scand[wid][lane];
                const float* cr = cb + (size_t)k * DIM;
                const float* x = lat + (size_t)n * DIM;
                float nk = nrmc[k];
                float af = 0.f, am = 0.f;
                for (int d = 0; d < DIM; ++d) {
                    float la = x[d] / nx;
                    float cv = cr[d] / nk;
                    af = fmaf(la, cv, af);
                    am = __fadd_rn(am, __fmul_rn(la, cv));
                }
                float df = __fsub_rn(2.0f, __fmul_rn(2.0f, af));
                float dm = __fsub_rn(2.0f, __fmul_rn(2.0f, am));
                keyf = ((ull)(0xFFFFFFFFu - f2ord(df)) << 32) | (ull)(0xFFFFFFFFu - (unsigned)k);
                keym = ((ull)(0xFFFFFFFFu - f2ord(dm)) << 32) | (ull)(0xFFFFFFFFu - (unsigned)k);
            }
#pragma unroll
            for (int off = 1; off < 64; off <<= 1) {
                ull of = __shfl_xor(keyf, off, 64);
                ull om = __shfl_xor(keym, off, 64);
                keyf = of > keyf ? of : keyf;
                keym = om > keym ? om : keym;
            }
            int colf = (int)(0xFFFFFFFFu - (unsigned)(keyf & 0xFFFFFFFFull));
            int colm = (int)(0xFFFFFFFFu - (unsigned)(keym & 0xFFFFFFFFull));
            idx = colf < colm ? colf : colm;
            selcos = 0.f;
            for (int c = 0; c < nc; ++c)
                if (scand[wid][c] == idx) selcos = (float)sc64[wid][c];
        }
    }
    // fused gather: idx is wave-uniform on every path
    float4 qv = *(const float4*)(cb + (size_t)idx * DIM + d0);
    *(float4*)(outq + (size_t)n * DIM + d0) = qv;
    float dx = xv.x - qv.x, dy = xv.y - qv.y, dz = xv.z - qv.z, dw = xv.w - qv.w;
    float msep = fmaf(dx, dx, fmaf(dy, dy, fmaf(dz, dz, dw * dw)));
#pragma unroll
    for (int off = 1; off < 64; off <<= 1) msep += __shfl_xor(msep, off, 64);
    if (lane == 0) {
        outidx[n] = (float)idx;
        atomicAdd(&counts[idx], 1u);
        selw[n] = selcos;
        msew[n] = msep;
    }
}

// ---- scalars: reduce all partial arrays ----
__global__ void finalize(const unsigned* __restrict__ counts,
                         const float* __restrict__ selw,
                         const float* __restrict__ msew,
                         const float* __restrict__ psumw,
                         const unsigned* __restrict__ pminw,
                         float* __restrict__ outs) {
    int t = threadIdx.x;
    __shared__ float red[256];
    float h = 0.f;
    for (int k = t; k < KCB; k += 256) {
        float p = (float)counts[k] * (1.0f / (float)NTOK);
        h += p * logf(p + 1e-10f);
    }
    red[t] = h; __syncthreads();
    for (int s = 128; s > 0; s >>= 1) { if (t < s) red[t] += red[t + s]; __syncthreads(); }
    float entNeg = red[0];
    __syncthreads();
    float ssel = 0.f;
    for (int k = t; k < NTOK; k += 256) ssel += selw[k];
    red[t] = ssel; __syncthreads();
    for (int s = 128; s > 0; s >>= 1) { if (t < s) red[t] += red[t + s]; __syncthreads(); }
    float selSum = red[0];
    __syncthreads();
    float sm = 0.f;
    for (int k = t; k < NTOK; k += 256) sm += msew[k];
    red[t] = sm; __syncthreads();
    for (int s = 128; s > 0; s >>= 1) { if (t < s) red[t] += red[t + s]; __syncthreads(); }
    float mseSum = red[0];
    __syncthreads();
    float ps = 0.f;
    for (int k = t; k < NPAIRB; k += 256) ps += psumw[k];
    red[t] = ps; __syncthreads();
    for (int s = 128; s > 0; s >>= 1) { if (t < s) red[t] += red[t + s]; __syncthreads(); }
    float pairSum = red[0];
    __syncthreads();
    unsigned pm = 0xFFFFFFFFu;
    for (int k = t; k < NPAIRB; k += 256) pm = min(pm, pminw[k]);
    ((unsigned*)red)[t] = pm; __syncthreads();
    for (int s = 128; s > 0; s >>= 1) {
        if (t < s) ((unsigned*)red)[t] = min(((unsigned*)red)[t], ((unsigned*)red)[t + s]);
        __syncthreads();
    }
    unsigned pairMin = ((unsigned*)red)[0];
    if (t == 0) {
        float mse = mseSum / (float)(NTOK * DIM);
        outs[0] = 0.25f * mse;
        outs[1] = mse;
        outs[2] = expf(-entNeg);
        outs[3] = selSum / (float)NTOK;
        outs[4] = pairSum * 2.0f / ((float)KCB * (float)(KCB - 1));
        outs[5] = ord2f(pairMin);
    }
}

extern "C" void kernel_launch(void* const* d_in, const int* in_sizes, int n_in,
                              void* d_out, int out_size, void* d_ws, size_t ws_size,
                              hipStream_t stream) {
    const float* latent = (const float*)d_in[0];    // [8192,256]
    const float* codebook = (const float*)d_in[1];  // [4096,256]
    float* out = (float*)d_out;
    float* outq = out;
    float* outidx = out + (size_t)NTOK * DIM;
    float* outs = outidx + NTOK;

    unsigned* keysw = (unsigned*)d_ws;                        // 128*8192 u32 = 4 MB
    ushort* latbf = (ushort*)(keysw + (size_t)NKROW * NTOK);  // 4 MB
    ushort* cnbf = latbf + (size_t)NTOK * DIM;                // 2 MB
    ushort* cbbf = cnbf + (size_t)KCB * DIM;                  // 2 MB
    float* nrml = (float*)(cbbf + (size_t)KCB * DIM);         // 8192
    float* nrmc = nrml + NTOK;                                // 4096
    float* sq = nrmc + KCB;                                   // 4096
    unsigned* counts = (unsigned*)(sq + KCB);                 // 4096
    float* selw = (float*)(counts + KCB);                     // 8192
    float* msew = selw + NTOK;                                // 8192
    float* psumw = msew + NTOK;                               // 528
    unsigned* pminw = (unsigned*)(psumw + NPAIRB);            // 528

    hipLaunchKernelGGL(prep, dim3(NTOK + KCB), dim3(256), 0, stream,
                       latent, codebook, nrml, nrmc, latbf, cnbf, cbbf, sq, counts);
    hipLaunchKernelGGL(gemms, dim3(NSCOB + NPAIRB), dim3(128), 0, stream,
                       latbf, cnbf, cbbf, sq, keysw, psumw, pminw);
    hipLaunchKernelGGL(argmax_resolve, dim3(NTOK / 4), dim3(256), 0, stream,
                       latent, codebook, nrml, nrmc, keysw, outidx, outq, counts, selw, msew);
    hipLaunchKernelGGL(finalize, dim3(1), dim3(256), 0, stream, counts, selw, msew, psumw, pminw, outs);
}